// Round 3
// baseline (453.406 us; speedup 1.0000x reference)
//
#include <hip/hip_runtime.h>
#include <cmath>
#include <cstdint>

#define BATCH  256
#define TT     1024
#define FIN    16
#define LSZ    256
#define NBULK  64
#define NCOH   32
#define TC     32
#define NCHUNK (TT / TC)
#define HS     257   // s_h row stride (floats)
#define YS     264   // s_y row stride (bf16)

typedef __attribute__((ext_vector_type(8))) short short8;
typedef __attribute__((ext_vector_type(4))) float floatx4;

__device__ __forceinline__ unsigned short f2bf(float f) {
    union { float f; unsigned int i; } v;
    v.f = f;
    unsigned int b = v.i;
    return (unsigned short)((b + 0x7FFFu + ((b >> 16) & 1u)) >> 16);  // RNE
}

// Material constants (plane stress, fp32-accurate)
#define MC00   219.78021978021977f   // E/(1-nu^2)
#define MC01   65.93406593406593f    // nu*E/(1-nu^2)
#define MC22   76.92307692307692f    // E/(1-nu^2)*(1-nu)/2
#define MI00   0.005f                // 1/E
#define MI01  -0.0015f               // -nu/E
#define MI22   0.013f                // 1/G
#define MSY0   2.0f
#define MHRD   10.0f
#define MINV3GH 0.0041533546325878594f  // 1/(3G+H)

__global__ __launch_bounds__(128, 1)
void fused_mat_kernel(const float* __restrict__ x,
                      const float* __restrict__ w1,
                      const float* __restrict__ w2,
                      float* __restrict__ out)
{
    __shared__ float          s_h[TC * HS];
    __shared__ unsigned short s_y[TC * YS];

    const int tid  = threadIdx.x;
    const int b    = blockIdx.x;
    const int lane = tid & 63;
    const int wv   = tid >> 6;    // 0 or 1
    const int m    = lane & 15;
    const int q    = lane >> 4;

    // ---- defensive LDS zero-init ----
    for (int idx = tid; idx < TC * HS; idx += 128) s_h[idx] = 0.0f;
    for (int idx = tid; idx < TC * YS; idx += 128) s_y[idx] = 0;

    // ---- one-time fragment setup (f32 loads, convert to bf16) ----
    // W1 B-fragments: B[k=f][n=l], element = W1[l = n*16+m][f = q*8+j], zero-pad k>=16
    short8 w1f[16];
    #pragma unroll
    for (int n = 0; n < 16; ++n) {
        #pragma unroll
        for (int j = 0; j < 8; ++j) {
            unsigned short v = 0;
            if (q < 2) v = f2bf(w1[(n * 16 + m) * FIN + q * 8 + j]);
            w1f[n][j] = (short)v;
        }
    }
    // softplus(W2) B-fragments: B[k=l][n=o], element = sp(W2[o=m][l = ks*32+q*8+j])
    short8 vf[8];
    #pragma unroll
    for (int ks = 0; ks < 8; ++ks) {
        #pragma unroll
        for (int j = 0; j < 8; ++j) {
            float xv = w2[m * LSZ + ks * 32 + q * 8 + j];
            float sp = fmaxf(xv, 0.0f) + log1pf(expf(-fabsf(xv)));
            vf[ks][j] = (short)f2bf(sp);
        }
    }

    // ---- persistent material state ----
    float p0 = 0.f, p1 = 0.f, p2 = 0.f, eb = 0.f;  // bulk (wave 0)
    float hist = 0.f;                               // cohesive (wave 1)

    __syncthreads();

    const size_t xrow = (size_t)b * TT;

    // software-pipelined x A-fragment: A[m=lane&15][k=q*8+j] = x[t][f], zero-pad k>=16
    short8 af;
    #pragma unroll
    for (int j = 0; j < 8; ++j) {
        unsigned short v = 0;
        if (q < 2) v = f2bf(x[(xrow + (0 + wv * 16 + m)) * FIN + q * 8 + j]);
        af[j] = (short)v;
    }

    for (int i = 0; i < NCHUNK; ++i) {
        const int t0 = i * TC;

        // ======== phase A: h-GEMM, wave wv computes t-rows [wv*16, wv*16+16) ========
        #pragma unroll
        for (int n = 0; n < 16; ++n) {
            floatx4 acc = {0.f, 0.f, 0.f, 0.f};
            acc = __builtin_amdgcn_mfma_f32_16x16x32_bf16(af, w1f[n], acc, 0, 0, 0);
            #pragma unroll
            for (int r = 0; r < 4; ++r)
                s_h[(wv * 16 + q * 4 + r) * HS + (n * 16 + m)] = acc[r];
        }

        // issue next chunk's x loads now; latency hides under phases B+C
        short8 af_next;
        #pragma unroll
        for (int j = 0; j < 8; ++j) {
            unsigned short v = 0;
            if (q < 2 && i + 1 < NCHUNK)
                v = f2bf(x[(xrow + ((i + 1) * TC + wv * 16 + m)) * FIN + q * 8 + j]);
            af_next[j] = (short)v;
        }

        __syncthreads();

        // ======== phase B: material scan over the chunk's TC steps ========
        if (wv == 0) {
            const int base = 3 * lane;
            float e0 = s_h[base + 0], e1 = s_h[base + 1], e2 = s_h[base + 2];
            for (int t = 0; t < TC; ++t) {
                float ne0 = 0.f, ne1 = 0.f, ne2 = 0.f;
                if (t + 1 < TC) {  // prefetch: address independent of state
                    const float* nr = s_h + (t + 1) * HS + base;
                    ne0 = nr[0]; ne1 = nr[1]; ne2 = nr[2];
                }
                float d0 = e0 - p0, d1 = e1 - p1, d2 = e2 - p2;
                float s0v = MC00 * d0 + MC01 * d1;
                float s1v = MC01 * d0 + MC00 * d1;
                float s2v = MC22 * d2;
                float qq  = fmaxf(s0v * s0v - s0v * s1v + s1v * s1v + 3.f * s2v * s2v, 1e-12f);
                float seq = sqrtf(qq);
                float sy  = MSY0 + MHRD * eb;
                float fy  = seq - sy;
                bool  pl  = fy > 0.f;
                float dep = pl ? fy * MINV3GH : 0.f;
                float rr  = pl ? (sy + MHRD * dep) / seq : 1.f;
                float g0 = rr * s0v, g1 = rr * s1v, g2 = rr * s2v;
                if (pl) {
                    p0 = e0 - (MI00 * g0 + MI01 * g1);
                    p1 = e1 - (MI01 * g0 + MI00 * g1);
                    p2 = e2 - MI22 * g2;
                }
                eb += dep;
                unsigned short* yr = s_y + t * YS + base;
                yr[0] = f2bf(g0); yr[1] = f2bf(g1); yr[2] = f2bf(g2);
                e0 = ne0; e1 = ne1; e2 = ne2;
            }
        } else if (lane < NCOH) {
            const int base = 3 * NBULK + 2 * lane;
            float dn = s_h[base + 0], ds = s_h[base + 1];
            for (int t = 0; t < TC; ++t) {
                float ndn = 0.f, nds = 0.f;
                if (t + 1 < TC) {
                    const float* nr = s_h + (t + 1) * HS + base;
                    ndn = nr[0]; nds = nr[1];
                }
                float dnp = fmaxf(dn, 0.f);
                float lam = sqrtf(fmaxf(dnp * dnp + ds * ds, 1e-12f));
                hist = fmaxf(hist, lam);
                float dmg = (hist - 0.1f) / (fmaxf(hist, 1e-12f) * 0.9f);
                dmg = fminf(fmaxf(dmg, 0.f), 1.f);
                float om = 1.f - dmg;
                float tn = 50.f * dn * (dn > 0.f ? om : 1.f);
                float ts = om * 50.f * ds;
                unsigned short* yr = s_y + t * YS + base;
                yr[0] = f2bf(tn); yr[1] = f2bf(ts);
                dn = ndn; ds = nds;
            }
        }

        __syncthreads();

        // ======== phase C: out-GEMM, wave wv computes t-rows [wv*16, wv*16+16) ========
        {
            floatx4 acc = {0.f, 0.f, 0.f, 0.f};
            #pragma unroll
            for (int ks = 0; ks < 8; ++ks) {
                short8 yf;
                const unsigned short* yp = s_y + (wv * 16 + m) * YS + ks * 32 + q * 8;
                #pragma unroll
                for (int j = 0; j < 8; ++j) yf[j] = (short)yp[j];
                acc = __builtin_amdgcn_mfma_f32_16x16x32_bf16(yf, vf[ks], acc, 0, 0, 0);
            }
            #pragma unroll
            for (int r = 0; r < 4; ++r) {
                const int t = t0 + wv * 16 + q * 4 + r;
                out[(xrow + t) * FIN + m] = acc[r];   // fp32 output
            }
        }

        af = af_next;
    }
}

extern "C" void kernel_launch(void* const* d_in, const int* in_sizes, int n_in,
                              void* d_out, int out_size, void* d_ws, size_t ws_size,
                              hipStream_t stream) {
    const float* x  = (const float*)d_in[0];   // [256,1024,16] f32
    const float* w1 = (const float*)d_in[1];   // [256,16] f32
    const float* w2 = (const float*)d_in[2];   // [16,256] f32
    float* out = (float*)d_out;                // [256,1024,16] f32
    fused_mat_kernel<<<BATCH, 128, 0, stream>>>(x, w1, w2, out);
}

// Round 4
// 197.421 us; speedup vs baseline: 2.2966x; 2.2966x over previous
//
#include <hip/hip_runtime.h>
#include <cmath>
#include <cstdint>

#define BATCH  256
#define TT     1024
#define FIN    16
#define LSZ    256
#define NBULK  64
#define NCOH   32
#define TC     16
#define NCHUNK (TT / TC)          // 64
#define HSS    260                // s_h f32 row stride (16B-aligned rows, <=2-way banks)
#define YSS    272                // s_y bf16 row stride (544B rows, 16B aligned for b128)

typedef __attribute__((ext_vector_type(8))) short short8;
typedef __attribute__((ext_vector_type(4))) float floatx4;

__device__ __forceinline__ unsigned short f2bf_rne(float f) {
    union { float f; unsigned int i; } v; v.f = f;
    unsigned int b = v.i;
    return (unsigned short)((b + 0x7FFFu + ((b >> 16) & 1u)) >> 16);
}
__device__ __forceinline__ unsigned short f2bf_hu(float f) {  // round-half-up: 2 ops, same 1/2-ulp bound
    union { float f; unsigned int i; } v; v.f = f;
    return (unsigned short)((v.i + 0x8000u) >> 16);
}

// Material constants (plane stress, fp32-accurate)
#define MC00   219.78021978021977f   // E/(1-nu^2)
#define MC01   65.93406593406593f    // nu*E/(1-nu^2)
#define MC22   76.92307692307692f    // E/(1-nu^2)*(1-nu)/2
#define MI00   0.005f                // 1/E
#define MI01  -0.0015f               // -nu/E
#define MI22   0.013f                // 1/G
#define MSY0   2.0f
#define MHRD   10.0f
#define MINV3GH 0.0041533546325878594f  // 1/(3G+H)

__global__ __launch_bounds__(256, 1)
void fused_mat_kernel(const float* __restrict__ x,
                      const float* __restrict__ w1,
                      const float* __restrict__ w2,
                      float* __restrict__ out)
{
    // double-buffered pipeline stages: producer(i+1) | material(i) | consumer(i-1)
    __shared__ __attribute__((aligned(16))) float          s_h[2][TC][HSS];  // 33280 B
    __shared__ __attribute__((aligned(16))) unsigned short s_y[2][TC][YSS];  // 17408 B

    const int tid  = threadIdx.x;
    const int b    = blockIdx.x;
    const int lane = tid & 63;
    const int wv   = tid >> 6;    // 0: bulk, 1: cohesive, 2: h-GEMM producer, 3: out-GEMM consumer
    const int m    = lane & 15;
    const int q    = lane >> 4;

    const size_t xrow = (size_t)b * TT;

    // ---------------- one-time per-wave setup ----------------
    short8 w1f[16];   // wave 2: B[k=f][n=l] = W1[n*16+m][q*8+j], zero-pad k>=16
    short8 vf[8];     // wave 3: B[k=l][n=o] = softplus(W2[m][ks*32+q*8+j])
    float p0 = 0.f, p1 = 0.f, p2 = 0.f, eb = 0.f;  // wave 0 state
    float hist = 0.f;                               // wave 1 state

    if (wv == 2) {
        #pragma unroll
        for (int n = 0; n < 16; ++n) {
            #pragma unroll
            for (int j = 0; j < 8; ++j) {
                unsigned short v = 0;
                if (q < 2) v = f2bf_rne(w1[(n * 16 + m) * FIN + q * 8 + j]);
                w1f[n][j] = (short)v;
            }
        }
        // prologue: produce chunk 0 into buffer 0
        short8 af;
        #pragma unroll
        for (int j = 0; j < 8; ++j) {
            unsigned short v = 0;
            if (q < 2) v = f2bf_rne(x[(xrow + m) * FIN + q * 8 + j]);
            af[j] = (short)v;
        }
        #pragma unroll
        for (int n = 0; n < 16; ++n) {
            floatx4 acc = {0.f, 0.f, 0.f, 0.f};
            acc = __builtin_amdgcn_mfma_f32_16x16x32_bf16(af, w1f[n], acc, 0, 0, 0);
            #pragma unroll
            for (int r = 0; r < 4; ++r)
                s_h[0][q * 4 + r][n * 16 + m] = acc[r];
        }
    } else if (wv == 3) {
        #pragma unroll
        for (int ks = 0; ks < 8; ++ks) {
            #pragma unroll
            for (int j = 0; j < 8; ++j) {
                float xv = w2[m * LSZ + ks * 32 + q * 8 + j];
                float sp = fmaxf(xv, 0.0f) + log1pf(expf(-fabsf(xv)));
                vf[ks][j] = (short)f2bf_rne(sp);
            }
        }
    }

    __syncthreads();   // chunk 0 of s_h visible

    // ---------------- pipelined main loop: 65 intervals, 1 barrier each ----------------
    for (int i = 0; i <= NCHUNK; ++i) {
        if (wv == 0) {
            if (i < NCHUNK) {
                // bulk J2: 64 chains, consume s_h[i&1], produce s_y[i&1]
                const float* hb = &s_h[i & 1][0][0];
                unsigned short* yb = &s_y[i & 1][0][0];
                const int base = 3 * lane;
                #pragma unroll
                for (int t = 0; t < TC; ++t) {
                    float e0 = hb[t * HSS + base + 0];
                    float e1 = hb[t * HSS + base + 1];
                    float e2 = hb[t * HSS + base + 2];
                    float d0 = e0 - p0, d1 = e1 - p1, d2 = e2 - p2;
                    float s0v = fmaf(MC01, d1, MC00 * d0);
                    float s1v = fmaf(MC00, d1, MC01 * d0);
                    float s2v = MC22 * d2;
                    float qq  = fmaf(s1v, s1v, fmaf(-s0v, s1v, s0v * s0v));
                    qq = fmaf(3.0f * s2v, s2v, qq);
                    qq = fmaxf(qq, 1e-12f);
                    float rs  = __builtin_amdgcn_rsqf(qq);   // 1/seq
                    float seq = qq * rs;                      // sqrt(qq)
                    float sy  = fmaf(MHRD, eb, MSY0);
                    float dep = fmaxf(seq - sy, 0.0f) * MINV3GH;
                    eb += dep;
                    float rr  = fminf(fmaf(MHRD, dep, sy) * rs, 1.0f); // elastic -> exactly 1
                    float g0 = rr * s0v, g1 = rr * s1v, g2 = rr * s2v;
                    // always-update epsp: elastic case returns p to ~itself (1e-7/step drift)
                    p0 = e0 - fmaf(MI01, g1, MI00 * g0);
                    p1 = e1 - fmaf(MI00, g1, MI01 * g0);
                    p2 = fmaf(-MI22, g2, e2);
                    yb[t * YSS + base + 0] = f2bf_hu(g0);
                    yb[t * YSS + base + 1] = f2bf_hu(g1);
                    yb[t * YSS + base + 2] = f2bf_hu(g2);
                }
            }
        } else if (wv == 1) {
            if (i < NCHUNK && lane < NCOH) {
                // cohesive: 32 chains
                const float* hb = &s_h[i & 1][0][0];
                unsigned short* yb = &s_y[i & 1][0][0];
                const int base = 3 * NBULK + 2 * lane;
                #pragma unroll
                for (int t = 0; t < TC; ++t) {
                    float dn = hb[t * HSS + base + 0];
                    float ds = hb[t * HSS + base + 1];
                    float dnp = fmaxf(dn, 0.0f);
                    float lam = sqrtf(fmaxf(fmaf(dnp, dnp, ds * ds), 1e-12f));
                    hist = fmaxf(hist, lam);   // hist >= 1e-6 afterwards
                    float dmg = (hist - 0.1f) * __builtin_amdgcn_rcpf(hist * 0.9f);
                    dmg = fminf(fmaxf(dmg, 0.0f), 1.0f);
                    float om = 1.0f - dmg;
                    float tn = 50.0f * dn * (dn > 0.0f ? om : 1.0f);
                    float ts = om * 50.0f * ds;
                    unsigned int pk = (unsigned int)f2bf_hu(tn) | ((unsigned int)f2bf_hu(ts) << 16);
                    *(unsigned int*)(yb + t * YSS + base) = pk;  // 4B-aligned: base even
                }
            }
        } else if (wv == 2) {
            if (i + 1 < NCHUNK) {
                // produce h chunk i+1 into s_h[(i+1)&1]
                const int tbase = (i + 1) * TC;
                float* hb = &s_h[(i + 1) & 1][0][0];
                short8 af;
                #pragma unroll
                for (int j = 0; j < 8; ++j) {
                    unsigned short v = 0;
                    if (q < 2) v = f2bf_rne(x[(xrow + tbase + m) * FIN + q * 8 + j]);
                    af[j] = (short)v;
                }
                #pragma unroll
                for (int n = 0; n < 16; ++n) {
                    floatx4 acc = {0.f, 0.f, 0.f, 0.f};
                    acc = __builtin_amdgcn_mfma_f32_16x16x32_bf16(af, w1f[n], acc, 0, 0, 0);
                    #pragma unroll
                    for (int r = 0; r < 4; ++r)
                        hb[(q * 4 + r) * HSS + n * 16 + m] = acc[r];
                }
            }
        } else {
            if (i >= 1) {
                // consume y chunk i-1 from s_y[(i-1)&1], write out
                const int t0 = (i - 1) * TC;
                const unsigned short* yb = &s_y[(i - 1) & 1][0][0];
                floatx4 acc = {0.f, 0.f, 0.f, 0.f};
                #pragma unroll
                for (int ks = 0; ks < 8; ++ks) {
                    const short8* yp = (const short8*)(yb + m * YSS + ks * 32 + q * 8);
                    acc = __builtin_amdgcn_mfma_f32_16x16x32_bf16(*yp, vf[ks], acc, 0, 0, 0);
                }
                #pragma unroll
                for (int r = 0; r < 4; ++r)
                    out[(xrow + t0 + q * 4 + r) * FIN + m] = acc[r];
            }
        }
        __syncthreads();
    }
}

extern "C" void kernel_launch(void* const* d_in, const int* in_sizes, int n_in,
                              void* d_out, int out_size, void* d_ws, size_t ws_size,
                              hipStream_t stream) {
    const float* x  = (const float*)d_in[0];   // [256,1024,16] f32
    const float* w1 = (const float*)d_in[1];   // [256,16] f32
    const float* w2 = (const float*)d_in[2];   // [16,256] f32
    float* out = (float*)d_out;                // [256,1024,16] f32
    fused_mat_kernel<<<BATCH, 256, 0, stream>>>(x, w1, w2, out);
}

// Round 5
// 190.697 us; speedup vs baseline: 2.3776x; 1.0353x over previous
//
#include <hip/hip_runtime.h>
#include <cmath>
#include <cstdint>

#define BATCH  256
#define TT     1024
#define FIN    16
#define LSZ    256
#define NBULK  64
#define NCOH   32
#define TC     16
#define NCHUNK (TT / TC)          // 64
#define YSS    336                // s_y row stride (bf16): 320 used + pad, 672B rows (16B aligned)

typedef __attribute__((ext_vector_type(8))) short short8;
typedef __attribute__((ext_vector_type(4))) float floatx4;

__device__ __forceinline__ unsigned short f2bf_rne(float f) {
    union { float f; unsigned int i; } v; v.f = f;
    unsigned int b = v.i;
    return (unsigned short)((b + 0x7FFFu + ((b >> 16) & 1u)) >> 16);
}
__device__ __forceinline__ unsigned int bfbits(float f) {  // round-half-up, full u32
    union { float f; unsigned int i; } v; v.f = f;
    return v.i + 0x8000u;
}

// Material constants (plane stress)
#define MC00   219.78021978021977f    // E/(1-nu^2)
#define MC01   65.93406593406593f     // nu*E/(1-nu^2)
#define MC22   76.92307692307692f     // E/(1-nu^2)*(1-nu)/2
#define MSY0   2.0f
#define AK     0.958466453674121406f  // 3G/(3G+H)
#define BK     0.041533546325878594f  // H/(3G+H)

__global__ __launch_bounds__(256, 1)
void fused_mat_kernel(const float* __restrict__ x,
                      const float* __restrict__ w1,
                      const float* __restrict__ w2,
                      float* __restrict__ out)
{
    // Pipeline buffers. Bulk strains: 16B slot per chain -> single b128 read/step.
    __shared__ __attribute__((aligned(16))) float          s_hb[2][TC][256];  // 32 KB
    __shared__ __attribute__((aligned(16))) float          s_hc[2][TC][64];   // 8 KB
    __shared__ __attribute__((aligned(16))) unsigned short s_y [2][TC][YSS];  // 21504 B

    const int tid  = threadIdx.x;
    const int b    = blockIdx.x;
    const int lane = tid & 63;
    const int wv   = tid >> 6;    // 0: bulk J2, 1: cohesive, 2: h-GEMM producer, 3: out-GEMM consumer
    const int m    = lane & 15;
    const int q    = lane >> 4;

    const size_t xrow = (size_t)b * TT;

    short8 w1f[16];   // wave 2
    short8 vf[10];    // wave 3 (permuted-k layout, 320 k-positions)
    short8 af;        // wave 2: prefetched x fragment for next chunk to produce

    // material state
    float sg0 = 0.f, sg1 = 0.f, sg2 = 0.f, syv = MSY0, ep0 = 0.f, ep1 = 0.f, ep2 = 0.f; // wave 0
    float hist = 0.f;                                                                    // wave 1

    if (wv == 2) {
        #pragma unroll
        for (int n = 0; n < 16; ++n) {
            #pragma unroll
            for (int j = 0; j < 8; ++j) {
                unsigned short v = 0;
                if (q < 2) v = f2bf_rne(w1[(n * 16 + m) * FIN + q * 8 + j]);
                w1f[n][j] = (short)v;
            }
        }
        // prologue: produce chunk 0 into buffer 0
        short8 a0;
        #pragma unroll
        for (int j = 0; j < 8; ++j) {
            unsigned short v = 0;
            if (q < 2) v = f2bf_rne(x[(xrow + m) * FIN + q * 8 + j]);
            a0[j] = (short)v;
        }
        #pragma unroll
        for (int n = 0; n < 16; ++n) {
            floatx4 acc = {0.f, 0.f, 0.f, 0.f};
            acc = __builtin_amdgcn_mfma_f32_16x16x32_bf16(a0, w1f[n], acc, 0, 0, 0);
            const int col = n * 16 + m;
            if (n < 12) {  // bulk cols 0..191
                const int c = col / 3, cm = col - c * 3;
                #pragma unroll
                for (int r = 0; r < 4; ++r) s_hb[0][q * 4 + r][c * 4 + cm] = acc[r];
            } else {       // cohesive cols 192..255
                #pragma unroll
                for (int r = 0; r < 4; ++r) s_hc[0][q * 4 + r][col - 192] = acc[r];
            }
        }
        // prefetch x for chunk 1
        #pragma unroll
        for (int j = 0; j < 8; ++j) {
            unsigned short v = 0;
            if (q < 2) v = f2bf_rne(x[(xrow + TC + m) * FIN + q * 8 + j]);
            af[j] = (short)v;
        }
    } else if (wv == 3) {
        // permuted-k softplus(W2) fragments: position p -> layer index l
        #pragma unroll
        for (int ks = 0; ks < 10; ++ks) {
            #pragma unroll
            for (int j = 0; j < 8; ++j) {
                const int p = ks * 32 + q * 8 + j;
                unsigned short v = 0;
                if (p < 256) {
                    const int comp = p & 3;
                    if (comp < 3) {
                        const int l = 3 * (p >> 2) + comp;
                        float xv = w2[m * LSZ + l];
                        float sp = fmaxf(xv, 0.0f) + log1pf(expf(-fabsf(xv)));
                        v = f2bf_rne(sp);
                    }
                } else {
                    const int l = p - 64;  // 192 + (p - 256)
                    float xv = w2[m * LSZ + l];
                    float sp = fmaxf(xv, 0.0f) + log1pf(expf(-fabsf(xv)));
                    v = f2bf_rne(sp);
                }
                vf[ks][j] = (short)v;
            }
        }
    }

    __syncthreads();   // chunk 0 visible

    for (int i = 0; i <= NCHUNK; ++i) {
        const int buf = i & 1;
        if (wv == 0) {
            if (i < NCHUNK) {
                const float* hb = &s_hb[buf][0][0];
                unsigned short* yb = &s_y[buf][0][0];
                #pragma unroll
                for (int t = 0; t < TC; ++t) {
                    const floatx4 ev = *(const floatx4*)(hb + t * 256 + lane * 4);
                    // off-chain: delta-stress from strain increment
                    const float d0 = ev.x - ep0, d1 = ev.y - ep1, d2 = ev.z - ep2;
                    ep0 = ev.x; ep1 = ev.y; ep2 = ev.z;
                    const float dl0 = fmaf(MC01, d1, MC00 * d0);
                    const float dl1 = fmaf(MC00, d1, MC01 * d0);
                    const float dl2 = MC22 * d2;
                    const float pre = AK * syv;          // off-chain (prev-step sy)
                    // dependent chain
                    const float t0 = sg0 + dl0, t1 = sg1 + dl1, t2 = sg2 + dl2;
                    float qq = t0 * t0;
                    qq = fmaf(-t0, t1, qq);
                    qq = fmaf(t1, t1, qq);
                    const float t2s = t2 * t2;
                    qq = fmaf(3.0f, t2s, qq);
                    qq = fmaxf(qq, 1e-12f);
                    const float rs  = __builtin_amdgcn_rsqf(qq);   // 1/seq
                    const float seq = qq * rs;
                    const float rr  = fminf(fmaf(pre, rs, BK), 1.0f);  // elastic -> exactly 1
                    sg0 = rr * t0; sg1 = rr * t1; sg2 = rr * t2;
                    syv = fmaf(BK, fmaxf(seq - syv, 0.0f), syv);
                    // pack (sig0,sig1,sig2,0) as one b64 write
                    uint2 pk;
                    pk.x = (bfbits(sg0) >> 16) | (bfbits(sg1) & 0xFFFF0000u);
                    pk.y = (bfbits(sg2) >> 16);
                    *(uint2*)(yb + t * YSS + lane * 4) = pk;
                }
            }
        } else if (wv == 1) {
            if (i < NCHUNK && lane < NCOH) {
                const float* hc = &s_hc[buf][0][0];
                unsigned short* yb = &s_y[buf][0][0];
                #pragma unroll
                for (int t = 0; t < TC; ++t) {
                    const float2 jv = *(const float2*)(hc + t * 64 + 2 * lane);
                    const float dn = jv.x, ds = jv.y;
                    const float dnp = fmaxf(dn, 0.0f);
                    const float lam = sqrtf(fmaxf(fmaf(dnp, dnp, ds * ds), 1e-12f));
                    hist = fmaxf(hist, lam);   // >= 1e-6 afterwards
                    float dmg = (hist - 0.1f) * __builtin_amdgcn_rcpf(hist * 0.9f);
                    dmg = fminf(fmaxf(dmg, 0.0f), 1.0f);
                    const float om = 1.0f - dmg;
                    const float tn = 50.0f * dn * (dn > 0.0f ? om : 1.0f);
                    const float ts = om * 50.0f * ds;
                    unsigned int pk = (bfbits(tn) >> 16) | (bfbits(ts) & 0xFFFF0000u);
                    *(unsigned int*)(yb + t * YSS + 256 + 2 * lane) = pk;
                }
            }
        } else if (wv == 2) {
            if (i + 1 < NCHUNK) {
                // produce h chunk i+1 from prefetched af
                float* hbw = &s_hb[(i + 1) & 1][0][0];
                float* hcw = &s_hc[(i + 1) & 1][0][0];
                #pragma unroll
                for (int n = 0; n < 16; ++n) {
                    floatx4 acc = {0.f, 0.f, 0.f, 0.f};
                    acc = __builtin_amdgcn_mfma_f32_16x16x32_bf16(af, w1f[n], acc, 0, 0, 0);
                    const int col = n * 16 + m;
                    if (n < 12) {
                        const int c = col / 3, cm = col - c * 3;
                        #pragma unroll
                        for (int r = 0; r < 4; ++r) hbw[(q * 4 + r) * 256 + c * 4 + cm] = acc[r];
                    } else {
                        #pragma unroll
                        for (int r = 0; r < 4; ++r) hcw[(q * 4 + r) * 64 + col - 192] = acc[r];
                    }
                }
                // prefetch x for chunk i+2 (drained at this interval's barrier)
                short8 afn;
                #pragma unroll
                for (int j = 0; j < 8; ++j) {
                    unsigned short v = 0;
                    if (q < 2 && i + 2 < NCHUNK)
                        v = f2bf_rne(x[(xrow + (i + 2) * TC + m) * FIN + q * 8 + j]);
                    afn[j] = (short)v;
                }
                af = afn;
            }
        } else {
            if (i >= 1) {
                // consume y chunk i-1, write out
                const int t0 = (i - 1) * TC;
                const unsigned short* yb = &s_y[(i - 1) & 1][0][0];
                floatx4 acc = {0.f, 0.f, 0.f, 0.f};
                #pragma unroll
                for (int ks = 0; ks < 10; ++ks) {
                    const short8* yp = (const short8*)(yb + m * YSS + ks * 32 + q * 8);
                    acc = __builtin_amdgcn_mfma_f32_16x16x32_bf16(*yp, vf[ks], acc, 0, 0, 0);
                }
                #pragma unroll
                for (int r = 0; r < 4; ++r)
                    out[(xrow + t0 + q * 4 + r) * FIN + m] = acc[r];
            }
        }
        __syncthreads();
    }
}

extern "C" void kernel_launch(void* const* d_in, const int* in_sizes, int n_in,
                              void* d_out, int out_size, void* d_ws, size_t ws_size,
                              hipStream_t stream) {
    const float* x  = (const float*)d_in[0];   // [256,1024,16] f32
    const float* w1 = (const float*)d_in[1];   // [256,16] f32
    const float* w2 = (const float*)d_in[2];   // [16,256] f32
    float* out = (float*)d_out;                // [256,1024,16] f32
    fused_mat_kernel<<<BATCH, 256, 0, stream>>>(x, w1, w2, out);
}